// Round 7
// baseline (84.234 us; speedup 1.0000x reference)
//
#include <hip/hip_runtime.h>
#include <math.h>

typedef float f2 __attribute__((ext_vector_type(2)));

// Problem constants
constexpr int NB = 64;      // batch
constexpr int NU = 2048;    // U
constexpr int ND = 1024;    // dec dim
constexpr int NE = 512;     // enc dim
constexpr int NH = 4;       // heads
constexpr int NK = 256;     // head dim
constexpr int NA = 1024;    // out dim
constexpr int NS = 16;      // U splits
constexpr int ROWS_PER_BLOCK = NU / NS;            // 128
constexpr int ROWS_PER_WAVE  = ROWS_PER_BLOCK / 4; // 32
constexpr float SCALE = 0.0625f;                   // 1/sqrt(256)

constexpr int RSPLIT = 16;
constexpr int RCH = (NH*NE)/RSPLIT;  // 128
constexpr int BT = 8;

constexpr int DSP = 16;   // D splits in k_phi (64 d each)

// workspace layout (float offsets)
constexpr size_t WS_Q   = 0;                            // q:      131072 floats
constexpr size_t WS_CTX = WS_Q + (size_t)NB*NH*NE;      // ctxacc: 131072 floats
constexpr size_t WS_P   = WS_CTX + (size_t)NB*NH*NE;    // phi partials: 16*64*4*256 = 1M floats

// ---------------------------------------------------------------------------
// K1a: phi partials. (unchanged)
__global__ __launch_bounds__(256) void k_phi(
    const float* __restrict__ dec, const float* __restrict__ phi_w,
    float* __restrict__ P, float* __restrict__ q, float* __restrict__ ctxacc,
    const float* __restrict__ out_b, float* __restrict__ out)
{
  const int flat = blockIdx.x;              // 0..255
  const int kc = flat & 3;
  const int h  = (flat >> 2) & 3;
  const int ds = flat >> 4;                 // 0..15
  const int t = threadIdx.x;

  // replay-safe inits (consumed by later kernels; kernel boundary orders them)
  ctxacc[(size_t)flat*512 + t]       = 0.f;
  ctxacc[(size_t)flat*512 + 256 + t] = 0.f;
  q[(size_t)flat*512 + t]            = 0.f;
  q[(size_t)flat*512 + 256 + t]      = 0.f;
  out[(size_t)flat*256 + t] = out_b[(flat*256 + t) & (NA-1)];

  const int d0 = ds*64, k0 = kc*64;

  __shared__ float phi_lds[64][64];   // 16 KB [d][k]
  __shared__ float dec_t[64][68];     // 17 KB [d][b]

  {
    const int kq = t & 15, r = t >> 4;        // r: 0..15
    const float* pwb = phi_w + ((size_t)h*ND + d0)*NK + k0;
    #pragma unroll
    for (int p = 0; p < 4; ++p) {
      float4 v = *(const float4*)(pwb + (size_t)(r + 16*p)*NK + 4*kq);
      *(float4*)&phi_lds[r + 16*p][4*kq] = v;
    }
    const float* db = dec + d0 + 4*kq;
    #pragma unroll
    for (int p = 0; p < 4; ++p) {
      const int b = r + 16*p;
      float4 v = *(const float4*)(db + (size_t)b*ND);
      dec_t[4*kq+0][b] = v.x; dec_t[4*kq+1][b] = v.y;
      dec_t[4*kq+2][b] = v.z; dec_t[4*kq+3][b] = v.w;
    }
  }
  __syncthreads();

  const int k = t & 63, bq = t >> 6, b0 = bq*16;
  f2 acc2[8];
  #pragma unroll
  for (int i = 0; i < 8; ++i) acc2[i] = f2{0.f, 0.f};
  #pragma unroll 4
  for (int d = 0; d < 64; ++d) {
    float w = phi_lds[d][k];
    f2 ww = f2{w, w};
    float4 a0 = *(const float4*)&dec_t[d][b0];
    float4 a1 = *(const float4*)&dec_t[d][b0+4];
    float4 a2 = *(const float4*)&dec_t[d][b0+8];
    float4 a3 = *(const float4*)&dec_t[d][b0+12];
    acc2[0] += f2{a0.x,a0.y}*ww; acc2[1] += f2{a0.z,a0.w}*ww;
    acc2[2] += f2{a1.x,a1.y}*ww; acc2[3] += f2{a1.z,a1.w}*ww;
    acc2[4] += f2{a2.x,a2.y}*ww; acc2[5] += f2{a2.z,a2.w}*ww;
    acc2[6] += f2{a3.x,a3.y}*ww; acc2[7] += f2{a3.z,a3.w}*ww;
  }
  float* pb = P + (((size_t)ds*64 + b0)*NH + h)*NK + k0 + k;
  #pragma unroll
  for (int j = 0; j < 8; ++j) {
    pb[(size_t)(2*j  )*NH*NK] = acc2[j][0];
    pb[(size_t)(2*j+1)*NH*NK] = acc2[j][1];
  }
}

// ---------------------------------------------------------------------------
// K1b: (unchanged)
__global__ __launch_bounds__(256) void k_q(
    const float* __restrict__ P, const float* __restrict__ phi_b,
    const float* __restrict__ psi_w, float* __restrict__ q)
{
  const int flat = blockIdx.x;              // 0..127
  const int ks = flat & 3;
  const int ec = (flat >> 2) & 7;
  const int h  = flat >> 5;
  const int t = threadIdx.x;
  const int k0 = ks*64, e0 = ec*64;

  __shared__ float phi_red[64][68];   // [k][b]
  __shared__ float psi_lds[64][65];   // [e][k]

  {
    const int e = t >> 2, kq4 = t & 3;
    const float* pb = psi_w + ((size_t)h*NE + e0 + e)*NK + k0 + 4*kq4;
    #pragma unroll
    for (int p = 0; p < 4; ++p) {
      float4 v = *(const float4*)(pb + 16*p);
      const int kk = 4*(kq4 + 4*p);
      psi_lds[e][kk+0] = v.x; psi_lds[e][kk+1] = v.y;
      psi_lds[e][kk+2] = v.z; psi_lds[e][kk+3] = v.w;
    }
  }
  {
    const int b = t >> 2, kq4 = t & 3;
    const float* pbase = P + ((size_t)b*NH + h)*NK + k0 + 4*kq4;
    #pragma unroll
    for (int p = 0; p < 4; ++p) {
      float4 s = make_float4(0.f, 0.f, 0.f, 0.f);
      #pragma unroll
      for (int dsi = 0; dsi < DSP; ++dsi) {
        float4 v = *(const float4*)(pbase + (size_t)dsi*64*NH*NK + 16*p);
        s.x += v.x; s.y += v.y; s.z += v.z; s.w += v.w;
      }
      const int kk = 4*(kq4 + 4*p);
      const float* bb = phi_b + h*NK + k0 + kk;
      phi_red[kk+0][b] = s.x + bb[0];
      phi_red[kk+1][b] = s.y + bb[1];
      phi_red[kk+2][b] = s.z + bb[2];
      phi_red[kk+3][b] = s.w + bb[3];
    }
  }
  __syncthreads();

  const int e = t & 63, bq = t >> 6, b0 = bq*16;
  f2 acc2[8];
  #pragma unroll
  for (int i = 0; i < 8; ++i) acc2[i] = f2{0.f, 0.f};
  #pragma unroll 4
  for (int kl = 0; kl < 64; ++kl) {
    float w = psi_lds[e][kl];
    f2 ww = f2{w, w};
    float4 a0 = *(const float4*)&phi_red[kl][b0];
    float4 a1 = *(const float4*)&phi_red[kl][b0+4];
    float4 a2 = *(const float4*)&phi_red[kl][b0+8];
    float4 a3 = *(const float4*)&phi_red[kl][b0+12];
    acc2[0] += f2{a0.x,a0.y}*ww; acc2[1] += f2{a0.z,a0.w}*ww;
    acc2[2] += f2{a1.x,a1.y}*ww; acc2[3] += f2{a1.z,a1.w}*ww;
    acc2[4] += f2{a2.x,a2.y}*ww; acc2[5] += f2{a2.z,a2.w}*ww;
    acc2[6] += f2{a3.x,a3.y}*ww; acc2[7] += f2{a3.z,a3.w}*ww;
  }
  float* qb = q + ((size_t)b0*NH + h)*NE + e0 + e;
  #pragma unroll
  for (int j = 0; j < 8; ++j) {
    unsafeAtomicAdd(qb + (size_t)(2*j  )*NH*NE, acc2[j][0]);
    unsafeAtomicAdd(qb + (size_t)(2*j+1)*NH*NE, acc2[j][1]);
  }
}

// ---------------------------------------------------------------------------
// K2 v6: LDS-ring prefetch, depth 3-in-flight. In-flight bytes no longer
// capped by VGPRs: global_load_lds stages 4KB row-pairs into a wave-private
// 4-slot LDS ring (16KB/wave, 64KB/block -> 2 blocks/CU -> ~96KB/CU in
// flight, 3x all prior versions). Counted vmcnt (12 steady, 8/4/0 only in
// tail) never drains the pipe mid-loop. Compute body = v4/v5 half-wave
// structure (10 shuffles/row, no broadcast in hot loop).
__device__ __forceinline__ f2 shflx(f2 v, int m) {
  return f2{__shfl_xor(v[0], m), __shfl_xor(v[1], m)};
}

__device__ __forceinline__ void waitv(int n) {   // n is compile-time in unrolled loop
  switch (n) {
    case 0:  asm volatile("s_waitcnt vmcnt(0)"  ::: "memory"); break;
    case 4:  asm volatile("s_waitcnt vmcnt(4)"  ::: "memory"); break;
    case 8:  asm volatile("s_waitcnt vmcnt(8)"  ::: "memory"); break;
    default: asm volatile("s_waitcnt vmcnt(12)" ::: "memory"); break;
  }
}

__device__ __forceinline__ void fcomp(const float4 (&x)[4],
                                      const f2 (&qv)[NH][8], f2 (&acc2)[NH][8]) {
  f2 xf[8];
  xf[0]=f2{x[0].x,x[0].y}; xf[1]=f2{x[0].z,x[0].w};
  xf[2]=f2{x[1].x,x[1].y}; xf[3]=f2{x[1].z,x[1].w};
  xf[4]=f2{x[2].x,x[2].y}; xf[5]=f2{x[2].z,x[2].w};
  xf[6]=f2{x[3].x,x[3].y}; xf[7]=f2{x[3].z,x[3].w};
  f2 p[NH];
  #pragma unroll
  for (int h = 0; h < NH; ++h) {
    p[h] = xf[0]*qv[h][0];
    #pragma unroll
    for (int j = 1; j < 8; ++j) p[h] += xf[j]*qv[h][j];
  }
  f2 d01 = f2{p[0][0]+p[0][1], p[1][0]+p[1][1]};
  f2 d23 = f2{p[2][0]+p[2][1], p[3][0]+p[3][1]};
  #pragma unroll
  for (int off = 1; off < 32; off <<= 1) {
    d01 += shflx(d01, off);
    d23 += shflx(d23, off);
  }
  const float w[NH] = {__expf(d01[0]), __expf(d01[1]),
                       __expf(d23[0]), __expf(d23[1])};
  #pragma unroll
  for (int h = 0; h < NH; ++h) {
    f2 ww = f2{w[h], w[h]};
    #pragma unroll
    for (int j = 0; j < 8; ++j) acc2[h][j] += ww*xf[j];
  }
}

__global__ __launch_bounds__(256) void k_flash(
    const float* __restrict__ enc, const float* __restrict__ qg,
    float* __restrict__ ctxacc)
{
  const int s = blockIdx.x;
  const int b = blockIdx.y;
  const int t = threadIdx.x;
  const int wave = t >> 6;
  const int lane = t & 63;
  const int half = lane >> 5;     // which row of the pair
  const int l32 = lane & 31;

  __shared__ float sbuf[4][4][1024];   // [wave][slot][row-pair 4KB] = 64 KB

  // q fragments, SCALE folded: lane owns cols {ch*128 + l32*4 .. +3}, ch=0..3
  f2 qv[NH][8];
  const float* qbase = qg + (size_t)b*NH*NE + 4*l32;
  #pragma unroll
  for (int h = 0; h < NH; ++h)
    #pragma unroll
    for (int ch = 0; ch < 4; ++ch) {
      float4 a = *(const float4*)(qbase + h*NE + ch*128);
      qv[h][2*ch]   = f2{a.x*SCALE, a.y*SCALE};
      qv[h][2*ch+1] = f2{a.z*SCALE, a.w*SCALE};
    }

  f2 acc2[NH][8];
  #pragma unroll
  for (int h = 0; h < NH; ++h)
    #pragma unroll
    for (int j = 0; j < 8; ++j) acc2[h][j] = f2{0.f, 0.f};

  const int u0 = s*ROWS_PER_BLOCK + wave*ROWS_PER_WAVE;
  const float* pairbase = enc + ((size_t)b*NU + u0)*NE;   // wave's 64 KB slab

  // stage row-pair p (4 KB contiguous) into ring slot sl: 4 x 1KB loads.
  // global src per-lane (base + lane*16B); LDS dst wave-uniform + HW lane*16.
  auto STAGE = [&](int p, int sl) {
    const float* src = pairbase + (size_t)p*1024 + 4*lane;
    float* dst = &sbuf[wave][sl][0];
    #pragma unroll
    for (int j = 0; j < 4; ++j) {
      __builtin_amdgcn_global_load_lds(
          (const __attribute__((address_space(1))) void*)(src + j*256),
          (__attribute__((address_space(3))) void*)(dst + j*256),
          16, 0, 0);
    }
  };

  constexpr int NIT = ROWS_PER_WAVE/2;   // 16 row-pairs
  STAGE(0, 0); STAGE(1, 1); STAGE(2, 2);  // 12 loads in flight
  #pragma unroll
  for (int i = 0; i < NIT; ++i) {
    if (i + 3 < NIT) STAGE(i + 3, (i + 3) & 3);
    const int rem = (NIT - 1 - i < 3) ? (NIT - 1 - i) : 3;  // slots still in flight
    waitv(4*rem);                        // steady state: vmcnt(12)
    __builtin_amdgcn_sched_barrier(0);
    const float* sp = &sbuf[wave][i & 3][half*512 + 4*l32];
    float4 x[4];
    x[0] = *(const float4*)(sp);
    x[1] = *(const float4*)(sp + 128);
    x[2] = *(const float4*)(sp + 256);
    x[3] = *(const float4*)(sp + 384);
    fcomp(x, qv, acc2);
  }

  // combine the two halves (same cols, different row sets): one-time shuffles
  #pragma unroll
  for (int h = 0; h < NH; ++h)
    #pragma unroll
    for (int j = 0; j < 8; ++j) acc2[h][j] += shflx(acc2[h][j], 32);

  // cross-wave reduce: reuse ring LDS as acc_lds[4][NH][NE] (32 KB of 64)
  __syncthreads();   // all waves done with their ring slots
  float* acc_lds = &sbuf[0][0][0];
  if (half == 0) {
    #pragma unroll
    for (int h = 0; h < NH; ++h)
      #pragma unroll
      for (int ch = 0; ch < 4; ++ch)
        *(float4*)&acc_lds[(wave*NH + h)*NE + ch*128 + 4*l32] =
            make_float4(acc2[h][2*ch][0], acc2[h][2*ch][1],
                        acc2[h][2*ch+1][0], acc2[h][2*ch+1][1]);
  }
  __syncthreads();
  float* cb = ctxacc + (size_t)b*(NH*NE);
  #pragma unroll
  for (int h = 0; h < NH; ++h) {
    #pragma unroll
    for (int eo = 0; eo < 2; ++eo) {
      int e = t + eo*256;
      float v = acc_lds[(0*NH + h)*NE + e] + acc_lds[(1*NH + h)*NE + e]
              + acc_lds[(2*NH + h)*NE + e] + acc_lds[(3*NH + h)*NE + e];
      unsafeAtomicAdd(&cb[h*NE + e], v);
    }
  }
}

// ---------------------------------------------------------------------------
// K3: (unchanged)
__global__ __launch_bounds__(256) void k_out(
    const float* __restrict__ ctxacc, const float* __restrict__ out_w,
    float* __restrict__ out)
{
  const int t = threadIdx.x;
  const int a = blockIdx.x*256 + t;
  const int b0 = blockIdx.y * BT;
  const int rc = blockIdx.z;
  const int h  = rc >> 2;
  const int e0 = (rc & 3) * RCH;

  __shared__ float rn_lds[BT];
  const int wv = t >> 6, lane = t & 63;
  {
    const int i = 2*wv + (lane >> 5);
    const int l32 = lane & 31;
    const float* row = ctxacc + (size_t)(b0+i)*(NH*NE) + (size_t)h*NE;
    float ss = 0.f;
    #pragma unroll
    for (int j = 0; j < 16; ++j) { float v = row[l32 + 32*j]; ss += v*v; }
    #pragma unroll
    for (int off = 1; off < 32; off <<= 1) ss += __shfl_xor(ss, off);
    if (l32 == 0) rn_lds[i] = rsqrtf(fmaxf(ss, 1e-12f));
  }
  __syncthreads();

  __shared__ float c_lds[RCH][BT];   // 4 KB
  for (int g = t; g < RCH*BT; g += 256) {
    const int r = g & (RCH-1), i = g >> 7;
    c_lds[r][i] = ctxacc[(size_t)(b0+i)*(NH*NE) + (size_t)h*NE + e0 + r] * rn_lds[i];
  }
  __syncthreads();

  float accv[BT];
  #pragma unroll
  for (int i = 0; i < BT; ++i) accv[i] = 0.f;
  const float* w = out_w + ((size_t)rc*RCH)*NA + a;
  #pragma unroll 8
  for (int r = 0; r < RCH; ++r) {
    float wvv = w[(size_t)r*NA];
    float4 ca = *(const float4*)&c_lds[r][0];
    float4 cb = *(const float4*)&c_lds[r][4];
    accv[0] += ca.x*wvv; accv[1] += ca.y*wvv; accv[2] += ca.z*wvv; accv[3] += ca.w*wvv;
    accv[4] += cb.x*wvv; accv[5] += cb.y*wvv; accv[6] += cb.z*wvv; accv[7] += cb.w*wvv;
  }
  #pragma unroll
  for (int i = 0; i < BT; ++i)
    unsafeAtomicAdd(&out[(size_t)(b0+i)*NA + a], accv[i]);
}

// ---------------------------------------------------------------------------
extern "C" void kernel_launch(void* const* d_in, const int* in_sizes, int n_in,
                              void* d_out, int out_size, void* d_ws, size_t ws_size,
                              hipStream_t stream) {
  const float* dec   = (const float*)d_in[0];
  const float* enc   = (const float*)d_in[1];
  const float* phi_w = (const float*)d_in[2];
  const float* phi_b = (const float*)d_in[3];
  const float* psi_w = (const float*)d_in[4];
  // d_in[5] = psi_b: constant over u -> cancels in softmax.
  const float* out_w = (const float*)d_in[6];
  const float* out_b = (const float*)d_in[7];
  float* out = (float*)d_out;
  float* ws = (float*)d_ws;
  float* q      = ws + WS_Q;
  float* ctxacc = ws + WS_CTX;
  float* P      = ws + WS_P;

  hipLaunchKernelGGL(k_phi,   dim3(NH*4*DSP),              dim3(256), 0, stream,
                     dec, phi_w, P, q, ctxacc, out_b, out);
  hipLaunchKernelGGL(k_q,     dim3(128),                   dim3(256), 0, stream,
                     P, phi_b, psi_w, q);
  hipLaunchKernelGGL(k_flash, dim3(NS, NB),                dim3(256), 0, stream,
                     enc, q, ctxacc);
  hipLaunchKernelGGL(k_out,   dim3(NA/256, NB/BT, RSPLIT), dim3(256), 0, stream,
                     ctxacc, out_w, out);
}

// Round 8
// 77.593 us; speedup vs baseline: 1.0856x; 1.0856x over previous
//
#include <hip/hip_runtime.h>
#include <math.h>

typedef float f2 __attribute__((ext_vector_type(2)));

// Problem constants
constexpr int NB = 64;      // batch
constexpr int NU = 2048;    // U
constexpr int ND = 1024;    // dec dim
constexpr int NE = 512;     // enc dim
constexpr int NH = 4;       // heads
constexpr int NK = 256;     // head dim
constexpr int NA = 1024;    // out dim
constexpr int NS = 16;      // U splits
constexpr int ROWS_PER_BLOCK = NU / NS;            // 128
constexpr int ROWS_PER_WAVE  = ROWS_PER_BLOCK / 4; // 32
constexpr float SCALE = 0.0625f;                   // 1/sqrt(256)

constexpr int RSPLIT = 16;
constexpr int RCH = (NH*NE)/RSPLIT;  // 128
constexpr int BT = 8;

constexpr int DSP = 16;   // D splits in k_phi (64 d each)

// workspace layout (float offsets)
constexpr size_t WS_Q   = 0;                            // q:      131072 floats
constexpr size_t WS_CTX = WS_Q + (size_t)NB*NH*NE;      // ctxacc: 131072 floats
constexpr size_t WS_P   = WS_CTX + (size_t)NB*NH*NE;    // phi partials: 16*64*4*256 = 1M floats

// ---------------------------------------------------------------------------
// K1a: phi partials. (unchanged)
__global__ __launch_bounds__(256) void k_phi(
    const float* __restrict__ dec, const float* __restrict__ phi_w,
    float* __restrict__ P, float* __restrict__ q, float* __restrict__ ctxacc,
    const float* __restrict__ out_b, float* __restrict__ out)
{
  const int flat = blockIdx.x;              // 0..255
  const int kc = flat & 3;
  const int h  = (flat >> 2) & 3;
  const int ds = flat >> 4;                 // 0..15
  const int t = threadIdx.x;

  // replay-safe inits (consumed by later kernels; kernel boundary orders them)
  ctxacc[(size_t)flat*512 + t]       = 0.f;
  ctxacc[(size_t)flat*512 + 256 + t] = 0.f;
  q[(size_t)flat*512 + t]            = 0.f;
  q[(size_t)flat*512 + 256 + t]      = 0.f;
  out[(size_t)flat*256 + t] = out_b[(flat*256 + t) & (NA-1)];

  const int d0 = ds*64, k0 = kc*64;

  __shared__ float phi_lds[64][64];   // 16 KB [d][k]
  __shared__ float dec_t[64][68];     // 17 KB [d][b]

  {
    const int kq = t & 15, r = t >> 4;        // r: 0..15
    const float* pwb = phi_w + ((size_t)h*ND + d0)*NK + k0;
    #pragma unroll
    for (int p = 0; p < 4; ++p) {
      float4 v = *(const float4*)(pwb + (size_t)(r + 16*p)*NK + 4*kq);
      *(float4*)&phi_lds[r + 16*p][4*kq] = v;
    }
    const float* db = dec + d0 + 4*kq;
    #pragma unroll
    for (int p = 0; p < 4; ++p) {
      const int b = r + 16*p;
      float4 v = *(const float4*)(db + (size_t)b*ND);
      dec_t[4*kq+0][b] = v.x; dec_t[4*kq+1][b] = v.y;
      dec_t[4*kq+2][b] = v.z; dec_t[4*kq+3][b] = v.w;
    }
  }
  __syncthreads();

  const int k = t & 63, bq = t >> 6, b0 = bq*16;
  f2 acc2[8];
  #pragma unroll
  for (int i = 0; i < 8; ++i) acc2[i] = f2{0.f, 0.f};
  #pragma unroll 4
  for (int d = 0; d < 64; ++d) {
    float w = phi_lds[d][k];
    f2 ww = f2{w, w};
    float4 a0 = *(const float4*)&dec_t[d][b0];
    float4 a1 = *(const float4*)&dec_t[d][b0+4];
    float4 a2 = *(const float4*)&dec_t[d][b0+8];
    float4 a3 = *(const float4*)&dec_t[d][b0+12];
    acc2[0] += f2{a0.x,a0.y}*ww; acc2[1] += f2{a0.z,a0.w}*ww;
    acc2[2] += f2{a1.x,a1.y}*ww; acc2[3] += f2{a1.z,a1.w}*ww;
    acc2[4] += f2{a2.x,a2.y}*ww; acc2[5] += f2{a2.z,a2.w}*ww;
    acc2[6] += f2{a3.x,a3.y}*ww; acc2[7] += f2{a3.z,a3.w}*ww;
  }
  float* pb = P + (((size_t)ds*64 + b0)*NH + h)*NK + k0 + k;
  #pragma unroll
  for (int j = 0; j < 8; ++j) {
    pb[(size_t)(2*j  )*NH*NK] = acc2[j][0];
    pb[(size_t)(2*j+1)*NH*NK] = acc2[j][1];
  }
}

// ---------------------------------------------------------------------------
// K1b: (unchanged)
__global__ __launch_bounds__(256) void k_q(
    const float* __restrict__ P, const float* __restrict__ phi_b,
    const float* __restrict__ psi_w, float* __restrict__ q)
{
  const int flat = blockIdx.x;              // 0..127
  const int ks = flat & 3;
  const int ec = (flat >> 2) & 7;
  const int h  = flat >> 5;
  const int t = threadIdx.x;
  const int k0 = ks*64, e0 = ec*64;

  __shared__ float phi_red[64][68];   // [k][b]
  __shared__ float psi_lds[64][65];   // [e][k]

  {
    const int e = t >> 2, kq4 = t & 3;
    const float* pb = psi_w + ((size_t)h*NE + e0 + e)*NK + k0 + 4*kq4;
    #pragma unroll
    for (int p = 0; p < 4; ++p) {
      float4 v = *(const float4*)(pb + 16*p);
      const int kk = 4*(kq4 + 4*p);
      psi_lds[e][kk+0] = v.x; psi_lds[e][kk+1] = v.y;
      psi_lds[e][kk+2] = v.z; psi_lds[e][kk+3] = v.w;
    }
  }
  {
    const int b = t >> 2, kq4 = t & 3;
    const float* pbase = P + ((size_t)b*NH + h)*NK + k0 + 4*kq4;
    #pragma unroll
    for (int p = 0; p < 4; ++p) {
      float4 s = make_float4(0.f, 0.f, 0.f, 0.f);
      #pragma unroll
      for (int dsi = 0; dsi < DSP; ++dsi) {
        float4 v = *(const float4*)(pbase + (size_t)dsi*64*NH*NK + 16*p);
        s.x += v.x; s.y += v.y; s.z += v.z; s.w += v.w;
      }
      const int kk = 4*(kq4 + 4*p);
      const float* bb = phi_b + h*NK + k0 + kk;
      phi_red[kk+0][b] = s.x + bb[0];
      phi_red[kk+1][b] = s.y + bb[1];
      phi_red[kk+2][b] = s.z + bb[2];
      phi_red[kk+3][b] = s.w + bb[3];
    }
  }
  __syncthreads();

  const int e = t & 63, bq = t >> 6, b0 = bq*16;
  f2 acc2[8];
  #pragma unroll
  for (int i = 0; i < 8; ++i) acc2[i] = f2{0.f, 0.f};
  #pragma unroll 4
  for (int kl = 0; kl < 64; ++kl) {
    float w = psi_lds[e][kl];
    f2 ww = f2{w, w};
    float4 a0 = *(const float4*)&phi_red[kl][b0];
    float4 a1 = *(const float4*)&phi_red[kl][b0+4];
    float4 a2 = *(const float4*)&phi_red[kl][b0+8];
    float4 a3 = *(const float4*)&phi_red[kl][b0+12];
    acc2[0] += f2{a0.x,a0.y}*ww; acc2[1] += f2{a0.z,a0.w}*ww;
    acc2[2] += f2{a1.x,a1.y}*ww; acc2[3] += f2{a1.z,a1.w}*ww;
    acc2[4] += f2{a2.x,a2.y}*ww; acc2[5] += f2{a2.z,a2.w}*ww;
    acc2[6] += f2{a3.x,a3.y}*ww; acc2[7] += f2{a3.z,a3.w}*ww;
  }
  float* qb = q + ((size_t)b0*NH + h)*NE + e0 + e;
  #pragma unroll
  for (int j = 0; j < 8; ++j) {
    unsafeAtomicAdd(qb + (size_t)(2*j  )*NH*NE, acc2[j][0]);
    unsafeAtomicAdd(qb + (size_t)(2*j+1)*NH*NE, acc2[j][1]);
  }
}

// ---------------------------------------------------------------------------
// K2 v7: v5's structure (half-wave rows, depth-4 register ring) with a
// DENSE-FRONT row permutation. Theory: all prior versions gave each wave a
// private 64KB slab -> instantaneous read front = ~4096 scattered 1-4KB
// grains -> DRAM row-buffer thrash caps effective BW at ~3.5 TB/s. Now
// wave-stream k = s*4+wave reads row-pair (i*64 + k) at iteration i: the 64
// streams of each batch cover a dense 128-row (256KB) window together, and
// each block's 4 waves read 16KB contiguous even with drift.
__device__ __forceinline__ f2 shflx(f2 v, int m) {
  return f2{__shfl_xor(v[0], m), __shfl_xor(v[1], m)};
}

__device__ __forceinline__ void fload(float4 (&r)[4], const float* myrow, int it) {
  const float* rp = myrow + (size_t)it*(64*2*NE);   // stride: 64 row-pairs
  r[0] = *(const float4*)(rp);
  r[1] = *(const float4*)(rp + 128);
  r[2] = *(const float4*)(rp + 256);
  r[3] = *(const float4*)(rp + 384);
}

__device__ __forceinline__ void fcomp(const float4 (&x)[4],
                                      const f2 (&qv)[NH][8], f2 (&acc2)[NH][8]) {
  f2 xf[8];
  xf[0]=f2{x[0].x,x[0].y}; xf[1]=f2{x[0].z,x[0].w};
  xf[2]=f2{x[1].x,x[1].y}; xf[3]=f2{x[1].z,x[1].w};
  xf[4]=f2{x[2].x,x[2].y}; xf[5]=f2{x[2].z,x[2].w};
  xf[6]=f2{x[3].x,x[3].y}; xf[7]=f2{x[3].z,x[3].w};
  f2 p[NH];
  #pragma unroll
  for (int h = 0; h < NH; ++h) {
    p[h] = xf[0]*qv[h][0];
    #pragma unroll
    for (int j = 1; j < 8; ++j) p[h] += xf[j]*qv[h][j];
  }
  f2 d01 = f2{p[0][0]+p[0][1], p[1][0]+p[1][1]};
  f2 d23 = f2{p[2][0]+p[2][1], p[3][0]+p[3][1]};
  #pragma unroll
  for (int off = 1; off < 32; off <<= 1) {
    d01 += shflx(d01, off);
    d23 += shflx(d23, off);
  }
  const float w[NH] = {__expf(d01[0]), __expf(d01[1]),
                       __expf(d23[0]), __expf(d23[1])};
  #pragma unroll
  for (int h = 0; h < NH; ++h) {
    f2 ww = f2{w[h], w[h]};
    #pragma unroll
    for (int j = 0; j < 8; ++j) acc2[h][j] += ww*xf[j];
  }
}

__global__ __launch_bounds__(256) void k_flash(
    const float* __restrict__ enc, const float* __restrict__ qg,
    float* __restrict__ ctxacc)
{
  const int s = blockIdx.x;
  const int b = blockIdx.y;
  const int t = threadIdx.x;
  const int wave = t >> 6;
  const int lane = t & 63;
  const int half = lane >> 5;     // which row of the pair
  const int l32 = lane & 31;

  // q fragments, SCALE folded: lane owns cols {ch*128 + l32*4 .. +3}, ch=0..3
  f2 qv[NH][8];
  const float* qbase = qg + (size_t)b*NH*NE + 4*l32;
  #pragma unroll
  for (int h = 0; h < NH; ++h)
    #pragma unroll
    for (int ch = 0; ch < 4; ++ch) {
      float4 a = *(const float4*)(qbase + h*NE + ch*128);
      qv[h][2*ch]   = f2{a.x*SCALE, a.y*SCALE};
      qv[h][2*ch+1] = f2{a.z*SCALE, a.w*SCALE};
    }

  f2 acc2[NH][8];
  #pragma unroll
  for (int h = 0; h < NH; ++h)
    #pragma unroll
    for (int j = 0; j < 8; ++j) acc2[h][j] = f2{0.f, 0.f};

  // dense-front stream: this wave's stream index k = s*4+wave; iteration i
  // reads row-pair (i*64 + k), i.e. rows 2*(i*64+k) + half.
  const int strm = s*4 + wave;    // 0..63
  const float* myrow = enc + ((size_t)b*NU + 2*strm + half)*NE + 4*l32;

  constexpr int NIT = ROWS_PER_WAVE/2;   // 16 row-pair iterations
  float4 R[4][4];                        // circular depth-4 buffer (64 VGPR)
  #pragma unroll
  for (int c = 0; c < 4; ++c) fload(R[c], myrow, c);
  #pragma unroll
  for (int i = 0; i < NIT; ++i) {        // full unroll: all R-indices static
    fcomp(R[i & 3], qv, acc2);
    if (i + 4 < NIT) fload(R[i & 3], myrow, i + 4);
  }

  // combine the two halves (same cols, different row sets): one-time shuffles
  #pragma unroll
  for (int h = 0; h < NH; ++h)
    #pragma unroll
    for (int j = 0; j < 8; ++j) acc2[h][j] += shflx(acc2[h][j], 32);

  // cross-wave reduce via LDS, then one atomicAdd per (h,e)
  __shared__ float acc_lds[4*NH*NE];   // 32 KB
  if (half == 0) {
    #pragma unroll
    for (int h = 0; h < NH; ++h)
      #pragma unroll
      for (int ch = 0; ch < 4; ++ch)
        *(float4*)&acc_lds[(wave*NH + h)*NE + ch*128 + 4*l32] =
            make_float4(acc2[h][2*ch][0], acc2[h][2*ch][1],
                        acc2[h][2*ch+1][0], acc2[h][2*ch+1][1]);
  }
  __syncthreads();
  float* cb = ctxacc + (size_t)b*(NH*NE);
  #pragma unroll
  for (int h = 0; h < NH; ++h) {
    #pragma unroll
    for (int eo = 0; eo < 2; ++eo) {
      int e = t + eo*256;
      float v = acc_lds[(0*NH + h)*NE + e] + acc_lds[(1*NH + h)*NE + e]
              + acc_lds[(2*NH + h)*NE + e] + acc_lds[(3*NH + h)*NE + e];
      unsafeAtomicAdd(&cb[h*NE + e], v);
    }
  }
}

// ---------------------------------------------------------------------------
// K3: (unchanged)
__global__ __launch_bounds__(256) void k_out(
    const float* __restrict__ ctxacc, const float* __restrict__ out_w,
    float* __restrict__ out)
{
  const int t = threadIdx.x;
  const int a = blockIdx.x*256 + t;
  const int b0 = blockIdx.y * BT;
  const int rc = blockIdx.z;
  const int h  = rc >> 2;
  const int e0 = (rc & 3) * RCH;

  __shared__ float rn_lds[BT];
  const int wv = t >> 6, lane = t & 63;
  {
    const int i = 2*wv + (lane >> 5);
    const int l32 = lane & 31;
    const float* row = ctxacc + (size_t)(b0+i)*(NH*NE) + (size_t)h*NE;
    float ss = 0.f;
    #pragma unroll
    for (int j = 0; j < 16; ++j) { float v = row[l32 + 32*j]; ss += v*v; }
    #pragma unroll
    for (int off = 1; off < 32; off <<= 1) ss += __shfl_xor(ss, off);
    if (l32 == 0) rn_lds[i] = rsqrtf(fmaxf(ss, 1e-12f));
  }
  __syncthreads();

  __shared__ float c_lds[RCH][BT];   // 4 KB
  for (int g = t; g < RCH*BT; g += 256) {
    const int r = g & (RCH-1), i = g >> 7;
    c_lds[r][i] = ctxacc[(size_t)(b0+i)*(NH*NE) + (size_t)h*NE + e0 + r] * rn_lds[i];
  }
  __syncthreads();

  float accv[BT];
  #pragma unroll
  for (int i = 0; i < BT; ++i) accv[i] = 0.f;
  const float* w = out_w + ((size_t)rc*RCH)*NA + a;
  #pragma unroll 8
  for (int r = 0; r < RCH; ++r) {
    float wvv = w[(size_t)r*NA];
    float4 ca = *(const float4*)&c_lds[r][0];
    float4 cb = *(const float4*)&c_lds[r][4];
    accv[0] += ca.x*wvv; accv[1] += ca.y*wvv; accv[2] += ca.z*wvv; accv[3] += ca.w*wvv;
    accv[4] += cb.x*wvv; accv[5] += cb.y*wvv; accv[6] += cb.z*wvv; accv[7] += cb.w*wvv;
  }
  #pragma unroll
  for (int i = 0; i < BT; ++i)
    unsafeAtomicAdd(&out[(size_t)(b0+i)*NA + a], accv[i]);
}

// ---------------------------------------------------------------------------
extern "C" void kernel_launch(void* const* d_in, const int* in_sizes, int n_in,
                              void* d_out, int out_size, void* d_ws, size_t ws_size,
                              hipStream_t stream) {
  const float* dec   = (const float*)d_in[0];
  const float* enc   = (const float*)d_in[1];
  const float* phi_w = (const float*)d_in[2];
  const float* phi_b = (const float*)d_in[3];
  const float* psi_w = (const float*)d_in[4];
  // d_in[5] = psi_b: constant over u -> cancels in softmax.
  const float* out_w = (const float*)d_in[6];
  const float* out_b = (const float*)d_in[7];
  float* out = (float*)d_out;
  float* ws = (float*)d_ws;
  float* q      = ws + WS_Q;
  float* ctxacc = ws + WS_CTX;
  float* P      = ws + WS_P;

  hipLaunchKernelGGL(k_phi,   dim3(NH*4*DSP),              dim3(256), 0, stream,
                     dec, phi_w, P, q, ctxacc, out_b, out);
  hipLaunchKernelGGL(k_q,     dim3(128),                   dim3(256), 0, stream,
                     P, phi_b, psi_w, q);
  hipLaunchKernelGGL(k_flash, dim3(NS, NB),                dim3(256), 0, stream,
                     enc, q, ctxacc);
  hipLaunchKernelGGL(k_out,   dim3(NA/256, NB/BT, RSPLIT), dim3(256), 0, stream,
                     ctxacc, out_w, out);
}